// Round 3
// baseline (965.329 us; speedup 1.0000x reference)
//
#include <hip/hip_runtime.h>
#include <math.h>

#define NB    4096
#define DD    2048
#define CLOC  128
#define PARTS 8
#define FEPS  1e-12f
#define FMARGIN 0.3f

// ---------------- kernel 1: row L2 normalize + sum(feats^2) ----------------
__global__ __launch_bounds__(256) void normalize_kernel(
    const float* __restrict__ x, float* __restrict__ feats, float* __restrict__ sq) {
  __shared__ float sm[4];
  const int row = blockIdx.x;
  const int t = threadIdx.x;
  const float* xr = x + (size_t)row * DD;
  float4 a = *(const float4*)(xr + 4 * t);
  float4 b = *(const float4*)(xr + 4 * (t + 256));
  float ss = a.x*a.x + a.y*a.y + a.z*a.z + a.w*a.w
           + b.x*b.x + b.y*b.y + b.z*b.z + b.w*b.w;
  for (int off = 32; off; off >>= 1) ss += __shfl_down(ss, off);
  const int lane = t & 63, wid = t >> 6;
  if (lane == 0) sm[wid] = ss;
  __syncthreads();
  const float tot = sm[0] + sm[1] + sm[2] + sm[3];
  const float inv = 1.0f / (sqrtf(tot) + FEPS);
  float4 fa, fb;
  fa.x = a.x*inv; fa.y = a.y*inv; fa.z = a.z*inv; fa.w = a.w*inv;
  fb.x = b.x*inv; fb.y = b.y*inv; fb.z = b.z*inv; fb.w = b.w*inv;
  float* fr = feats + (size_t)row * DD;
  *(float4*)(fr + 4 * t) = fa;
  *(float4*)(fr + 4 * (t + 256)) = fb;
  float s2 = fa.x*fa.x + fa.y*fa.y + fa.z*fa.z + fa.w*fa.w
           + fb.x*fb.x + fb.y*fb.y + fb.z*fb.z + fb.w*fb.w;
  __syncthreads();  // sm reuse
  for (int off = 32; off; off >>= 1) s2 += __shfl_down(s2, off);
  if (lane == 0) sm[wid] = s2;
  __syncthreads();
  if (t == 0) sq[row] = sm[0] + sm[1] + sm[2] + sm[3];
}

// ------- kernel 2: fused Gram tile + euclidean dist + hard mining ----------
// 128x128 block tile, BK=32, transposed LDS [k][m] (conflict-free b128 reads),
// 8x8 per-thread tile split as 2x2 blocks of 4x4 at offsets {0,64}.
#define BM 128
#define BN 128
#define BK 32
#define LDT 132          // word stride of transposed LDS rows
#define NCHUNK 16
#define CHUNK_COLS 256   // 2 col-tiles of 128 per block

__global__ __launch_bounds__(256, 2) void dist_mine_kernel(
    const float* __restrict__ feats, const float* __restrict__ sq,
    const int* __restrict__ targets,
    float* __restrict__ pap, int* __restrict__ papi,
    float* __restrict__ pan, int* __restrict__ pani) {
  __shared__ float sAT[BK * LDT];
  __shared__ float sBT[BK * LDT];
  const int tid = threadIdx.x;
  const int ty = tid >> 4, tx = tid & 15;     // 0..15 each
  const int ty4 = ty * 4, tx4 = tx * 4;
  const int rowtile = blockIdx.x >> 4;
  const int chunk = blockIdx.x & 15;
  const int row0 = rowtile * BM;
  const int chunk0 = chunk * CHUNK_COLS;

  // staging slot (fixed per thread): 4 float4 per matrix
  int mM[4], wB[4];
#pragma unroll
  for (int u = 0; u < 4; ++u) {
    const int ff = tid + u * 256;             // 0..1023 float4 slots
    const int m = ff >> 3, k4 = ff & 7;       // m: 0..127 row, k4: float4 slot in k
    mM[u] = m;
    wB[u] = (k4 * 4) * LDT + m;               // LDS word base for transposed scatter
  }

  // mining state for 8 rows: group g in {0,1} -> rows row0 + g*64 + ty4 + r
  float bap[2][4], ban[2][4], msq[2][4];
  int bapi[2][4], bani[2][4], mtg[2][4];
#pragma unroll
  for (int g = 0; g < 2; ++g)
#pragma unroll
    for (int r = 0; r < 4; ++r) {
      const int row = row0 + g * 64 + ty4 + r;
      msq[g][r] = sq[row]; mtg[g][r] = targets[row];
      bap[g][r] = -INFINITY; bapi[g][r] = 0;
      ban[g][r] = INFINITY;  bani[g][r] = 0;
    }

  for (int ct = 0; ct < CHUNK_COLS / BN; ++ct) {
    const int col0 = chunk0 + ct * BN;
    float acc[2][2][4][4] = {};               // [rowblk][colblk][r][c]
    for (int kk = 0; kk < DD; kk += BK) {
      __syncthreads();
#pragma unroll
      for (int u = 0; u < 4; ++u) {
        const int ff = tid + u * 256;
        const int k4 = ff & 7;
        const float4 va = *(const float4*)(feats + (size_t)(row0 + mM[u]) * DD + kk + k4 * 4);
        const float4 vb = *(const float4*)(feats + (size_t)(col0 + mM[u]) * DD + kk + k4 * 4);
        const float* vap = (const float*)&va;
        const float* vbp = (const float*)&vb;
#pragma unroll
        for (int j = 0; j < 4; ++j) {
          sAT[wB[u] + j * LDT] = vap[j];
          sBT[wB[u] + j * LDT] = vbp[j];
        }
      }
      __syncthreads();
#pragma unroll 8
      for (int k = 0; k < BK; ++k) {
        const float4 a0 = *(const float4*)&sAT[k * LDT + ty4];
        const float4 a1 = *(const float4*)&sAT[k * LDT + 64 + ty4];
        const float4 b0 = *(const float4*)&sBT[k * LDT + tx4];
        const float4 b1 = *(const float4*)&sBT[k * LDT + 64 + tx4];
        const float* ap0 = (const float*)&a0;
        const float* ap1 = (const float*)&a1;
        const float* bp0 = (const float*)&b0;
        const float* bp1 = (const float*)&b1;
#pragma unroll
        for (int r = 0; r < 4; ++r)
#pragma unroll
          for (int c = 0; c < 4; ++c) {
            acc[0][0][r][c] += ap0[r] * bp0[c];
            acc[0][1][r][c] += ap0[r] * bp1[c];
            acc[1][0][r][c] += ap1[r] * bp0[c];
            acc[1][1][r][c] += ap1[r] * bp1[c];
          }
      }
    }
    // epilogue: distances + mining; columns in increasing order (tie = first idx)
#pragma unroll
    for (int cg = 0; cg < 2; ++cg) {
      const int colbase = col0 + cg * 64 + tx4;
      float sqc[4]; int tgc[4];
#pragma unroll
      for (int c = 0; c < 4; ++c) { sqc[c] = sq[colbase + c]; tgc[c] = targets[colbase + c]; }
#pragma unroll
      for (int g = 0; g < 2; ++g)
#pragma unroll
        for (int r = 0; r < 4; ++r)
#pragma unroll
          for (int c = 0; c < 4; ++c) {
            const float d2 = msq[g][r] + sqc[c] - 2.0f * acc[g][cg][r][c];
            const float dist = sqrtf(fmaxf(d2, FEPS));
            const int col = colbase + c;
            if (tgc[c] == mtg[g][r]) {
              if (dist > bap[g][r]) { bap[g][r] = dist; bapi[g][r] = col; }
            } else {
              if (dist < ban[g][r]) { ban[g][r] = dist; bani[g][r] = col; }
            }
          }
    }
  }
  // reduce across the 16 tx lanes (contiguous within a wave) sharing rows
#pragma unroll
  for (int off = 1; off < 16; off <<= 1) {
#pragma unroll
    for (int g = 0; g < 2; ++g)
#pragma unroll
      for (int r = 0; r < 4; ++r) {
        float v = __shfl_xor(bap[g][r], off); int i2 = __shfl_xor(bapi[g][r], off);
        if (v > bap[g][r] || (v == bap[g][r] && i2 < bapi[g][r])) { bap[g][r] = v; bapi[g][r] = i2; }
        float w = __shfl_xor(ban[g][r], off); int j2 = __shfl_xor(bani[g][r], off);
        if (w < ban[g][r] || (w == ban[g][r] && j2 < bani[g][r])) { ban[g][r] = w; bani[g][r] = j2; }
      }
  }
  if (tx == 0) {
#pragma unroll
    for (int g = 0; g < 2; ++g)
#pragma unroll
      for (int r = 0; r < 4; ++r) {
        const int row = row0 + g * 64 + ty4 + r;
        pap[row * NCHUNK + chunk] = bap[g][r]; papi[row * NCHUNK + chunk] = bapi[g][r];
        pan[row * NCHUNK + chunk] = ban[g][r]; pani[row * NCHUNK + chunk] = bani[g][r];
      }
  }
}

// ---------------- kernel 3: reduce the 16 per-chunk partials ----------------
__global__ __launch_bounds__(256) void mine_reduce_kernel(
    const float* __restrict__ pap, const int* __restrict__ papi,
    const float* __restrict__ pan, const int* __restrict__ pani,
    float* __restrict__ dap, float* __restrict__ dan,
    int* __restrict__ pidx, int* __restrict__ nidx) {
  const int row = blockIdx.x * 256 + threadIdx.x;
  if (row >= NB) return;
  float bap = -INFINITY, ban = INFINITY;
  int bapi = 0, bani = 0;
#pragma unroll
  for (int c = 0; c < NCHUNK; ++c) {
    const float v = pap[row * NCHUNK + c]; const int i2 = papi[row * NCHUNK + c];
    if (v > bap || (v == bap && i2 < bapi)) { bap = v; bapi = i2; }
    const float w = pan[row * NCHUNK + c]; const int j2 = pani[row * NCHUNK + c];
    if (w < ban || (w == ban && j2 < bani)) { ban = w; bani = j2; }
  }
  dap[row] = bap; dan[row] = ban; pidx[row] = bapi; nidx[row] = bani;
}

// ------------- kernel 4: aligned local distance (8x8 DTW DP) ---------------
__global__ __launch_bounds__(64) void local_dist_kernel(
    const float* __restrict__ lf,   // [N][C=128][P=8]
    const int* __restrict__ pidx, const int* __restrict__ nidx,
    float* __restrict__ lap, float* __restrict__ lan) {
  const int i = blockIdx.x;
  const int j = (blockIdx.y == 0) ? pidx[i] : nidx[i];
  __shared__ float X[CLOC * PARTS];  // flat [c*8+p]
  __shared__ float Y[CLOC * PARTS];
  __shared__ float DM[64];
  const int t = threadIdx.x;
  const float* xi = lf + (size_t)i * (CLOC * PARTS);
  const float* yj = lf + (size_t)j * (CLOC * PARTS);
  for (int e = t; e < CLOC * PARTS; e += 64) { X[e] = xi[e]; Y[e] = yj[e]; }
  __syncthreads();
  const int p = t >> 3, q = t & 7;
  float xx = 0.f, yy = 0.f, xy = 0.f;
#pragma unroll 8
  for (int c = 0; c < CLOC; ++c) {
    const float xv = X[c * 8 + p], yv = Y[c * 8 + q];
    xx += xv * xv; yy += yv * yv; xy += xv * yv;
  }
  const float d2 = xx + yy - 2.0f * xy;
  const float dist = sqrtf(fmaxf(d2, FEPS));
  DM[p * 8 + q] = tanhf(0.5f * dist);   // (e^d-1)/(e^d+1) == tanh(d/2)
  __syncthreads();
  if (t == 0) {
    float row[8];
    row[0] = DM[0];
    for (int c = 1; c < 8; ++c) row[c] = row[c - 1] + DM[c];
    for (int r = 1; r < 8; ++r) {
      row[0] += DM[r * 8];
      for (int c = 1; c < 8; ++c) row[c] = fminf(row[c], row[c - 1]) + DM[r * 8 + c];
    }
    ((blockIdx.y == 0) ? lap : lan)[i] = row[7];
  }
}

// ---------------- kernel 5: margin ranking losses (means) ------------------
__global__ __launch_bounds__(256) void loss_kernel(
    const float* __restrict__ dap, const float* __restrict__ dan,
    const float* __restrict__ lap, const float* __restrict__ lan,
    float* __restrict__ out) {
  __shared__ float sm1[4], sm2[4];
  const int t = threadIdx.x;
  float s1 = 0.f, s2 = 0.f;
  for (int i = t; i < NB; i += 256) {
    s1 += fmaxf(0.f, FMARGIN - (dan[i] - dap[i]));
    s2 += fmaxf(0.f, FMARGIN - (lan[i] - lap[i]));
  }
  for (int off = 32; off; off >>= 1) { s1 += __shfl_down(s1, off); s2 += __shfl_down(s2, off); }
  const int lane = t & 63, wid = t >> 6;
  if (lane == 0) { sm1[wid] = s1; sm2[wid] = s2; }
  __syncthreads();
  if (t == 0) {
    out[0] = (sm1[0] + sm1[1] + sm1[2] + sm1[3]) * (1.0f / NB);
    out[1] = (sm2[0] + sm2[1] + sm2[2] + sm2[3]) * (1.0f / NB);
  }
}

extern "C" void kernel_launch(void* const* d_in, const int* in_sizes, int n_in,
                              void* d_out, int out_size, void* d_ws, size_t ws_size,
                              hipStream_t stream) {
  const float* inputs = (const float*)d_in[0];
  const int* targets = (const int*)d_in[1];
  const float* localf = (const float*)d_in[2];
  float* out = (float*)d_out;

  // workspace carve (~33.2 MB)
  float* feats = (float*)d_ws;                 // N*D
  float* sq    = feats + (size_t)NB * DD;      // N
  float* pap   = sq + NB;                      // N*16
  int*   papi  = (int*)(pap + (size_t)NB * NCHUNK);
  float* pan   = (float*)(papi + (size_t)NB * NCHUNK);
  int*   pani  = (int*)(pan + (size_t)NB * NCHUNK);
  float* dap   = (float*)(pani + (size_t)NB * NCHUNK);
  float* dan   = dap + NB;
  int*   pidx  = (int*)(dan + NB);
  int*   nidx  = pidx + NB;
  float* lap   = (float*)(nidx + NB);
  float* lan   = lap + NB;

  normalize_kernel<<<NB, 256, 0, stream>>>(inputs, feats, sq);
  dist_mine_kernel<<<32 * NCHUNK, 256, 0, stream>>>(feats, sq, targets, pap, papi, pan, pani);
  mine_reduce_kernel<<<NB / 256, 256, 0, stream>>>(pap, papi, pan, pani, dap, dan, pidx, nidx);
  local_dist_kernel<<<dim3(NB, 2), 64, 0, stream>>>(localf, pidx, nidx, lap, lan);
  loss_kernel<<<1, 256, 0, stream>>>(dap, dan, lap, lan, out);
}

// Round 10
// 319.625 us; speedup vs baseline: 3.0202x; 3.0202x over previous
//
#include <hip/hip_runtime.h>
#include <hip/hip_bf16.h>
#include <math.h>

#define NB    4096
#define DD    2048
#define CLOC  128
#define PARTS 8
#define FEPS  1e-12f
#define FMARGIN 0.3f
#define NCHUNK 16

typedef short bf16x8 __attribute__((ext_vector_type(8)));   // 8 bf16 bit-patterns (4 VGPRs)
typedef float f32x4 __attribute__((ext_vector_type(4)));

#define GLD16(g, l) __builtin_amdgcn_global_load_lds(                          \
    (const __attribute__((address_space(1))) void*)(g),                        \
    (__attribute__((address_space(3))) void*)(l), 16, 0, 0)

// ---- kernel 1: L2 normalize + split x = H + L, packed [j=k/8][row] ---------
// Hp/Lp layout: uint4 index = j*NB + row holds bf16 k = 8j..8j+7 of `row`.
__global__ __launch_bounds__(256) void normalize_pack_kernel(
    const float* __restrict__ x, uint4* __restrict__ Hp, uint4* __restrict__ Lp,
    float* __restrict__ sq) {
  __shared__ float sm[4];
  const int t = threadIdx.x;
  const int lane = t & 63, wid = t >> 6;
  const int r0 = blockIdx.x * 4;
  uint4 hreg[4], lreg[4];
#pragma unroll
  for (int q = 0; q < 4; ++q) {
    const int row = r0 + q;
    const float* xr = x + (size_t)row * DD + 8 * t;
    const float4 a = *(const float4*)xr;
    const float4 b = *(const float4*)(xr + 4);
    float v[8] = {a.x, a.y, a.z, a.w, b.x, b.y, b.z, b.w};
    float ss = 0.f;
#pragma unroll
    for (int j = 0; j < 8; ++j) ss += v[j] * v[j];
    for (int off = 32; off; off >>= 1) ss += __shfl_down(ss, off);
    if (lane == 0) sm[wid] = ss;
    __syncthreads();
    const float tot = sm[0] + sm[1] + sm[2] + sm[3];
    __syncthreads();  // sm reused next q
    const float inv = 1.0f / (sqrtf(tot) + FEPS);
    if (t == 0) sq[row] = tot * inv * inv;
    unsigned int hw[4], lw[4];
#pragma unroll
    for (int jp = 0; jp < 4; ++jp) {
      const float f0 = v[2 * jp] * inv, f1 = v[2 * jp + 1] * inv;
      const __hip_bfloat16 h0 = __float2bfloat16(f0), h1 = __float2bfloat16(f1);
      const float l0 = f0 - __bfloat162float(h0);
      const float l1 = f1 - __bfloat162float(h1);
      const __hip_bfloat16 g0 = __float2bfloat16(l0), g1 = __float2bfloat16(l1);
      hw[jp] = (unsigned)__builtin_bit_cast(unsigned short, h0) |
               ((unsigned)__builtin_bit_cast(unsigned short, h1) << 16);
      lw[jp] = (unsigned)__builtin_bit_cast(unsigned short, g0) |
               ((unsigned)__builtin_bit_cast(unsigned short, g1) << 16);
    }
    hreg[q] = make_uint4(hw[0], hw[1], hw[2], hw[3]);
    lreg[q] = make_uint4(lw[0], lw[1], lw[2], lw[3]);
  }
  uint4* hd = Hp + (size_t)t * NB + r0;
  uint4* ld = Lp + (size_t)t * NB + r0;
#pragma unroll
  for (int q = 0; q < 4; ++q) { hd[q] = hreg[q]; ld[q] = lreg[q]; }
}

// ---- kernel 2: split-bf16 MFMA Gram + distances + hard mining --------------
// 128x128 tile, 4 waves (2x2 of 64x64), KSTEP=32, dbuf global_load_lds staging.
// LDS buffer (32KB): plane q in {AH,AL,BH,BL} of 8KB; within plane:
// s*2048 + r*16 bytes (s = k-octet 0..3, r = tile row 0..127) -> frag-major:
// ds_read_b128 frag loads conflict-free, staging linear (rule 21 by construction).
#define BMT 128
#define KSTEP 32
#define NKT (DD / KSTEP)   // 64
#define CHUNK_COLS 256

__global__ __launch_bounds__(256, 2) void dist_mine_mfma(
    const uint4* __restrict__ Hp, const uint4* __restrict__ Lp,
    const float* __restrict__ sq, const int* __restrict__ targets,
    float* __restrict__ pap, int* __restrict__ papi,
    float* __restrict__ pan, int* __restrict__ pani) {
  __shared__ __attribute__((aligned(16))) char lds[2][32768];
  __shared__ float redv[2][2][BMT];  // [pos/neg][wc][row_local]
  __shared__ int   redi[2][2][BMT];
  const int tid = threadIdx.x;
  const int lane = tid & 63;
  const int w = tid >> 6;
  const int wr = w >> 1, wc = w & 1;
  const int g = lane >> 4, cl = lane & 15;
  const int rowtile = blockIdx.x >> 4;
  const int chunk = blockIdx.x & 15;
  const int row0 = rowtile * BMT;
  const int chunk0 = chunk * CHUNK_COLS;

  float bap[16], ban[16];
  int bapi[16], bani[16];
#pragma unroll
  for (int k = 0; k < 16; ++k) {
    bap[k] = -INFINITY; ban[k] = INFINITY; bapi[k] = 0; bani[k] = 0;
  }

  auto stage = [&](int p) {
    const int ct = p >> 6, kt = p & (NKT - 1);
    const int col0 = chunk0 + ct * BMT;
    const int r = tid & 127;
    const int shalf = tid >> 7;  // 0/1
    char* lbase = lds[p & 1];
#pragma unroll
    for (int u = 0; u < 8; ++u) {
      const int q = u >> 1;
      const int s = (u & 1) * 2 + shalf;
      const int baserow = (q & 2) ? col0 : row0;
      const uint4* src = (q & 1) ? Lp : Hp;
      const uint4* gp = src + (size_t)(kt * 4 + s) * NB + baserow + r;
      GLD16(gp, lbase + u * 4096 + tid * 16);
    }
  };

  stage(0);
  __syncthreads();

  f32x4 acc[4][4];
#pragma unroll
  for (int m = 0; m < 4; ++m)
#pragma unroll
    for (int n = 0; n < 4; ++n) acc[m][n] = (f32x4){0.f, 0.f, 0.f, 0.f};

  for (int p = 0; p < 2 * NKT; ++p) {
    if (p + 1 < 2 * NKT) stage(p + 1);
    const char* base = lds[p & 1];
    const int aoff = g * 2048 + (wr * 64 + cl) * 16;
    const int boff = g * 2048 + (wc * 64 + cl) * 16;
    bf16x8 aH[4], bH[4], aL[4], bL[4];
    // pass 1: HH
#pragma unroll
    for (int m = 0; m < 4; ++m) aH[m] = *(const bf16x8*)(base + aoff + m * 256);
#pragma unroll
    for (int n = 0; n < 4; ++n) bH[n] = *(const bf16x8*)(base + 16384 + boff + n * 256);
#pragma unroll
    for (int m = 0; m < 4; ++m)
#pragma unroll
      for (int n = 0; n < 4; ++n)
        acc[m][n] = __builtin_amdgcn_mfma_f32_16x16x32_bf16(aH[m], bH[n], acc[m][n], 0, 0, 0);
    // pass 2: LH
#pragma unroll
    for (int m = 0; m < 4; ++m) aL[m] = *(const bf16x8*)(base + 8192 + aoff + m * 256);
#pragma unroll
    for (int m = 0; m < 4; ++m)
#pragma unroll
      for (int n = 0; n < 4; ++n)
        acc[m][n] = __builtin_amdgcn_mfma_f32_16x16x32_bf16(aL[m], bH[n], acc[m][n], 0, 0, 0);
    // pass 3: HL
#pragma unroll
    for (int n = 0; n < 4; ++n) bL[n] = *(const bf16x8*)(base + 24576 + boff + n * 256);
#pragma unroll
    for (int m = 0; m < 4; ++m)
#pragma unroll
      for (int n = 0; n < 4; ++n)
        acc[m][n] = __builtin_amdgcn_mfma_f32_16x16x32_bf16(aH[m], bL[n], acc[m][n], 0, 0, 0);
    __syncthreads();

    if ((p & (NKT - 1)) == NKT - 1) {
      const int ct = p >> 6;
      const int colb = chunk0 + ct * BMT + wc * 64;
#pragma unroll
      for (int n = 0; n < 4; ++n) {
        const int col = colb + n * 16 + cl;
        const float sqc = sq[col];
        const int tgc = targets[col];
#pragma unroll
        for (int m = 0; m < 4; ++m)
#pragma unroll
          for (int i = 0; i < 4; ++i) {
            const int rrow = row0 + wr * 64 + m * 16 + g * 4 + i;
            const float d2 = sq[rrow] + sqc - 2.0f * acc[m][n][i];
            const float dist = sqrtf(fmaxf(d2, FEPS));
            const int k16 = m * 4 + i;
            if (tgc == targets[rrow]) {
              if (dist > bap[k16]) { bap[k16] = dist; bapi[k16] = col; }
            } else {
              if (dist < ban[k16]) { ban[k16] = dist; bani[k16] = col; }
            }
          }
      }
      if (ct == 0) {
#pragma unroll
        for (int m = 0; m < 4; ++m)
#pragma unroll
          for (int n = 0; n < 4; ++n) acc[m][n] = (f32x4){0.f, 0.f, 0.f, 0.f};
      }
    }
  }

  // reduce over the 16-lane col group (masks 1,2,4,8 stay in-group)
#pragma unroll
  for (int off = 1; off < 16; off <<= 1) {
#pragma unroll
    for (int k = 0; k < 16; ++k) {
      const float v = __shfl_xor(bap[k], off); const int vi = __shfl_xor(bapi[k], off);
      if (v > bap[k] || (v == bap[k] && vi < bapi[k])) { bap[k] = v; bapi[k] = vi; }
      const float u2 = __shfl_xor(ban[k], off); const int ui = __shfl_xor(bani[k], off);
      if (u2 < ban[k] || (u2 == ban[k] && ui < bani[k])) { ban[k] = u2; bani[k] = ui; }
    }
  }
  if (cl == 0) {
#pragma unroll
    for (int m = 0; m < 4; ++m)
#pragma unroll
      for (int i = 0; i < 4; ++i) {
        const int rl = wr * 64 + m * 16 + g * 4 + i;
        redv[0][wc][rl] = bap[m * 4 + i]; redi[0][wc][rl] = bapi[m * 4 + i];
        redv[1][wc][rl] = ban[m * 4 + i]; redi[1][wc][rl] = bani[m * 4 + i];
      }
  }
  __syncthreads();
  if (tid < BMT) {
    const int row = row0 + tid;
    float pv = redv[0][0][tid]; int pi = redi[0][0][tid];
    const float v1 = redv[0][1][tid]; const int i1 = redi[0][1][tid];
    if (v1 > pv || (v1 == pv && i1 < pi)) { pv = v1; pi = i1; }
    float nv = redv[1][0][tid]; int ni = redi[1][0][tid];
    const float v2 = redv[1][1][tid]; const int i2 = redi[1][1][tid];
    if (v2 < nv || (v2 == nv && i2 < ni)) { nv = v2; ni = i2; }
    pap[row * NCHUNK + chunk] = pv; papi[row * NCHUNK + chunk] = pi;
    pan[row * NCHUNK + chunk] = nv; pani[row * NCHUNK + chunk] = ni;
  }
}

// ---------------- kernel 3: reduce the 16 per-chunk partials ----------------
__global__ __launch_bounds__(256) void mine_reduce_kernel(
    const float* __restrict__ pap, const int* __restrict__ papi,
    const float* __restrict__ pan, const int* __restrict__ pani,
    float* __restrict__ dap, float* __restrict__ dan,
    int* __restrict__ pidx, int* __restrict__ nidx) {
  const int row = blockIdx.x * 256 + threadIdx.x;
  if (row >= NB) return;
  float bap = -INFINITY, ban = INFINITY;
  int bapi = 0, bani = 0;
#pragma unroll
  for (int c = 0; c < NCHUNK; ++c) {
    const float v = pap[row * NCHUNK + c]; const int i2 = papi[row * NCHUNK + c];
    if (v > bap || (v == bap && i2 < bapi)) { bap = v; bapi = i2; }
    const float w = pan[row * NCHUNK + c]; const int j2 = pani[row * NCHUNK + c];
    if (w < ban || (w == ban && j2 < bani)) { ban = w; bani = j2; }
  }
  dap[row] = bap; dan[row] = ban; pidx[row] = bapi; nidx[row] = bani;
}

// ------------- kernel 4: aligned local distance (8x8 DTW DP) ---------------
__global__ __launch_bounds__(64) void local_dist_kernel(
    const float* __restrict__ lf,   // [N][C=128][P=8]
    const int* __restrict__ pidx, const int* __restrict__ nidx,
    float* __restrict__ lap, float* __restrict__ lan) {
  const int i = blockIdx.x;
  const int j = (blockIdx.y == 0) ? pidx[i] : nidx[i];
  __shared__ float X[CLOC * PARTS];
  __shared__ float Y[CLOC * PARTS];
  __shared__ float DM[64];
  const int t = threadIdx.x;
  const float* xi = lf + (size_t)i * (CLOC * PARTS);
  const float* yj = lf + (size_t)j * (CLOC * PARTS);
  for (int e = t; e < CLOC * PARTS; e += 64) { X[e] = xi[e]; Y[e] = yj[e]; }
  __syncthreads();
  const int p = t >> 3, q = t & 7;
  float xx = 0.f, yy = 0.f, xy = 0.f;
#pragma unroll 8
  for (int c = 0; c < CLOC; ++c) {
    const float xv = X[c * 8 + p], yv = Y[c * 8 + q];
    xx += xv * xv; yy += yv * yv; xy += xv * yv;
  }
  const float d2 = xx + yy - 2.0f * xy;
  const float dist = sqrtf(fmaxf(d2, FEPS));
  DM[p * 8 + q] = tanhf(0.5f * dist);
  __syncthreads();
  if (t == 0) {
    float row[8];
    row[0] = DM[0];
    for (int c = 1; c < 8; ++c) row[c] = row[c - 1] + DM[c];
    for (int r = 1; r < 8; ++r) {
      row[0] += DM[r * 8];
      for (int c = 1; c < 8; ++c) row[c] = fminf(row[c], row[c - 1]) + DM[r * 8 + c];
    }
    ((blockIdx.y == 0) ? lap : lan)[i] = row[7];
  }
}

// ---------------- kernel 5: margin ranking losses (means) ------------------
__global__ __launch_bounds__(256) void loss_kernel(
    const float* __restrict__ dap, const float* __restrict__ dan,
    const float* __restrict__ lap, const float* __restrict__ lan,
    float* __restrict__ out) {
  __shared__ float sm1[4], sm2[4];
  const int t = threadIdx.x;
  float s1 = 0.f, s2 = 0.f;
  for (int i = t; i < NB; i += 256) {
    s1 += fmaxf(0.f, FMARGIN - (dan[i] - dap[i]));
    s2 += fmaxf(0.f, FMARGIN - (lan[i] - lap[i]));
  }
  for (int off = 32; off; off >>= 1) { s1 += __shfl_down(s1, off); s2 += __shfl_down(s2, off); }
  const int lane = t & 63, wid = t >> 6;
  if (lane == 0) { sm1[wid] = s1; sm2[wid] = s2; }
  __syncthreads();
  if (t == 0) {
    out[0] = (sm1[0] + sm1[1] + sm1[2] + sm1[3]) * (1.0f / NB);
    out[1] = (sm2[0] + sm2[1] + sm2[2] + sm2[3]) * (1.0f / NB);
  }
}

extern "C" void kernel_launch(void* const* d_in, const int* in_sizes, int n_in,
                              void* d_out, int out_size, void* d_ws, size_t ws_size,
                              hipStream_t stream) {
  const float* inputs = (const float*)d_in[0];
  const int* targets = (const int*)d_in[1];
  const float* localf = (const float*)d_in[2];
  float* out = (float*)d_out;

  // workspace carve (~33.1 MB)
  uint4* Hp  = (uint4*)d_ws;                       // 256*4096 uint4 = 16 MB
  uint4* Lp  = Hp + (size_t)(DD / 8) * NB;         // 16 MB
  float* sq  = (float*)(Lp + (size_t)(DD / 8) * NB);
  float* pap = sq + NB;
  int*   papi = (int*)(pap + (size_t)NB * NCHUNK);
  float* pan  = (float*)(papi + (size_t)NB * NCHUNK);
  int*   pani = (int*)(pan + (size_t)NB * NCHUNK);
  float* dap  = (float*)(pani + (size_t)NB * NCHUNK);
  float* dan  = dap + NB;
  int*   pidx = (int*)(dan + NB);
  int*   nidx = pidx + NB;
  float* lap  = (float*)(nidx + NB);
  float* lan  = lap + NB;

  normalize_pack_kernel<<<NB / 4, 256, 0, stream>>>(inputs, Hp, Lp, sq);
  dist_mine_mfma<<<(NB / BMT) * NCHUNK, 256, 0, stream>>>(Hp, Lp, sq, targets,
                                                          pap, papi, pan, pani);
  mine_reduce_kernel<<<NB / 256, 256, 0, stream>>>(pap, papi, pan, pani, dap, dan, pidx, nidx);
  local_dist_kernel<<<dim3(NB, 2), 64, 0, stream>>>(localf, pidx, nidx, lap, lan);
  loss_kernel<<<1, 256, 0, stream>>>(dap, dan, lap, lan, out);
}